// Round 11
// baseline (861.005 us; speedup 1.0000x reference)
//
#include <hip/hip_runtime.h>
#include <hip/hip_bf16.h>

typedef __bf16 bf16_t;
typedef __bf16 bf16x4 __attribute__((ext_vector_type(4)));
typedef __bf16 bf16x8 __attribute__((ext_vector_type(8)));
typedef float  f32x4  __attribute__((ext_vector_type(4)));

#define NH    6
#define CH    192
#define HW    112
#define SHIFT 3

// LDS strides (bf16 elems). XLD=200 -> 400B rows; ULD=72 -> 144B rows.
#define XLD 200
#define ULD 72

// Layout: X | {T overlay VOt}. P lives in registers (psave -> Y B-frag trick).
#define X_OFF   0                     // [64][200] = 12800
#define T_OFF   (64 * XLD)            // T [64][200] = 12800; VOt [192][72] = 13824
#define VOT_OFF T_OFF
#define LDS_ELEMS (T_OFF + 192 * ULD) // 26624
#define LDS_BYTES (LDS_ELEMS * 2)     // 53248 B = 52 KiB -> 3 blocks/CU

// ws: Gt swizzled (NH*CH*CH bf16) | U swizzled (NH*CH*CH bf16) | bu | w1
// Swizzled fragment layout: [h][tile(12)][ks(6)][lane(64)][e(8)] so one wave
// A-fragment load = contiguous 1024 B.
#define U_OFF_ELEMS  (NH * CH * CH)
#define BU_OFF_BYTES (2 * NH * CH * CH * 2)
#define W1_OFF_BYTES (BU_OFF_BYTES + NH * CH * 4)

// ---- prep: Gt[h][c'][c] = sum_d Wk[c',h,d] * Wq[c,h,d], written SWIZZLED ---
__global__ void prep_gt(const float* __restrict__ Wq, const float* __restrict__ Wk,
                        bf16_t* __restrict__ gt) {
  __shared__ float wk_row[CH];
  int h = blockIdx.x / CH, cp = blockIdx.x % CH;
  int c = threadIdx.x;
  wk_row[c] = Wk[(cp * NH + h) * CH + c];
  __syncthreads();
  float acc = 0.f;
  for (int d = 0; d < CH; ++d)
    acc += wk_row[d] * Wq[(c * NH + h) * CH + d];
  int tile = cp >> 4, l15 = cp & 15;
  int ks = c >> 5, lg = (c >> 3) & 3, e = c & 7;
  gt[((((h * 12 + tile) * 6 + ks) << 6) + lg * 16 + l15) * 8 + e] = (bf16_t)acc;
}

// ---- prep: U^h = Wv^h x Wo^h, rows c_out, cols c_in, written SWIZZLED ------
__global__ void prep_u(const float* __restrict__ Wv, const float* __restrict__ Wo,
                       bf16_t* __restrict__ u_out) {
  __shared__ float wv_row[CH];
  int h = blockIdx.x / CH, ci = blockIdx.x % CH;
  int t = threadIdx.x;                            // c_out
  wv_row[t] = Wv[(ci * NH + h) * CH + t];
  __syncthreads();
  float acc = 0.f;
  for (int d = 0; d < CH; ++d)
    acc += wv_row[d] * Wo[(h * CH + d) * CH + t];
  int tile = t >> 4, l15 = t & 15;
  int ks = ci >> 5, lg = (ci >> 3) & 3, e = ci & 7;
  u_out[((((h * 12 + tile) * 6 + ks) << 6) + lg * 16 + l15) * 8 + e] = (bf16_t)acc;
}

// ---- prep: bu^h = bv^h x Wo^h ---------------------------------------------
__global__ void prep_bu(const float* __restrict__ bv, const float* __restrict__ Wo,
                        float* __restrict__ bu) {
  int h = blockIdx.x, c = threadIdx.x;
  float acc = 0.f;
  for (int d = 0; d < CH; ++d)
    acc += bv[h * CH + d] * Wo[(h * CH + d) * CH + c];
  bu[h * CH + c] = acc;
}

// ---- prep: w1^h[c'] = sum_d Wk[c',h,d] * bq[h,d] ---------------------------
__global__ void prep_w1(const float* __restrict__ Wk, const float* __restrict__ bq,
                        float* __restrict__ w1) {
  int h = blockIdx.x, cp = threadIdx.x;
  float acc = 0.f;
  for (int d = 0; d < CH; ++d)
    acc += Wk[(cp * NH + h) * CH + d] * bq[h * CH + d];
  w1[h * CH + cp] = acc;
}

// ---- fused swin block: one 4-wave workgroup per 7x7 window, 3 blocks/CU ----
__global__ __launch_bounds__(256, 3) void swin_fused(
    const float* __restrict__ x,
    const float* __restrict__ bo,
    const bf16_t* __restrict__ wts,     // Gt | U (both swizzled)
    const float* __restrict__ bu, const float* __restrict__ w1,
    float* __restrict__ out) {
  extern __shared__ char smem_raw[];
  bf16_t* lds  = (bf16_t*)smem_raw;
  bf16_t* Xl   = lds + X_OFF;
  bf16_t* Tl   = lds + T_OFF;
  bf16_t* VOtl = lds + VOT_OFF;   // overlay (valid after B2)

  const int tid  = threadIdx.x;
  const int wave = tid >> 6;           // 0..3
  const int lane = tid & 63;
  const int l15  = lane & 15;
  const int lg   = lane >> 4;          // 0..3

  const int blk = blockIdx.x;
  const int b   = blk >> 8;
  const int rem = blk & 255;
  const int wi  = rem >> 4, wj = rem & 15;

  // zero pad rows 49..63 of X
  for (int idx = tid; idx < 15 * 100; idx += 256) {
    int row = 49 + idx / 100, c2 = (idx % 100) * 2;
    *(unsigned int*)&Xl[row * XLD + c2] = 0u;
  }
  // stage window tokens (roll -3,-3 folded into the gather), f32 -> bf16
  for (int idx = tid; idx < 49 * 48; idx += 256) {
    int t = idx / 48, q4 = idx % 48;
    int hs = wi * 7 + t / 7 + SHIFT; if (hs >= HW) hs -= HW;
    int ws2 = wj * 7 + t % 7 + SHIFT; if (ws2 >= HW) ws2 -= HW;
    const float4 v = *(const float4*)&x[(((b * HW + hs) * HW) + ws2) * CH + q4 * 4];
    bf16x4 pk = { (bf16_t)v.x, (bf16_t)v.y, (bf16_t)v.z, (bf16_t)v.w };
    *(bf16x4*)&Xl[t * XLD + q4 * 4] = pk;
  }

  const int wm = wave * 3;             // 3 c'/c-tiles owned per wave
  const float scale = 0.07216878364870322f;  // 1/sqrt(192)
  f32x4 yacc[12] = {};                 // persistent: own t-tile x 192 channels

  for (int h = 0; h < NH; ++h) {
    __syncthreads();   // (1) Y's VOt reads drained before T(h) overwrites
    // ---- Phase T: T[i][c'] = sum_c X[i,c] Gt[c',c] (+w1). Per-i-tile passes
    // (acc 12 regs live). Weight A-frags = contiguous 1KB loads.
    {
      const bf16_t* gt = wts;
      const float* w1h = w1 + h * CH;
#pragma unroll
      for (int ni = 0; ni < 4; ++ni) {
        f32x4 acc[3] = {};
#pragma unroll
        for (int ks = 0; ks < 6; ++ks) {
          bf16x8 bfr = *(const bf16x8*)&Xl[(ni * 16 + l15) * XLD + ks * 32 + lg * 8];
#pragma unroll
          for (int mi = 0; mi < 3; ++mi) {
            bf16x8 af = *(const bf16x8*)&gt[((((h * 12 + wm + mi) * 6 + ks) << 6) + lane) * 8];
            acc[mi] = __builtin_amdgcn_mfma_f32_16x16x32_bf16(af, bfr, acc[mi], 0, 0, 0);
          }
        }
        int i = ni * 16 + l15;
        if (i < 49) {
#pragma unroll
          for (int mi = 0; mi < 3; ++mi) {
            int cp0 = (wm + mi) * 16 + lg * 4;
            const f32x4 ww = *(const f32x4*)&w1h[cp0];
            bf16x4 pk = { (bf16_t)(acc[mi][0] + ww[0]), (bf16_t)(acc[mi][1] + ww[1]),
                          (bf16_t)(acc[mi][2] + ww[2]), (bf16_t)(acc[mi][3] + ww[3]) };
            *(bf16x4*)&Tl[i * XLD + cp0] = pk;
          }
        }
      }
    }
    __syncthreads();   // (2) T ready
    // ---- Phase S: S[i,j] = sum_c' X[j,c'] T[i,c'], i-tile = wave.
    // In-register softmax -> psave (P never touches LDS).
    bf16x4 psave[4];
    {
      f32x4 sacc[4] = {};
#pragma unroll
      for (int ks = 0; ks < 6; ++ks) {
        bf16x8 bt = *(const bf16x8*)&Tl[(wave * 16 + l15) * XLD + ks * 32 + lg * 8];
#pragma unroll
        for (int mj = 0; mj < 4; ++mj) {
          bf16x8 af = *(const bf16x8*)&Xl[(mj * 16 + l15) * XLD + ks * 32 + lg * 8];
          sacc[mj] = __builtin_amdgcn_mfma_f32_16x16x32_bf16(af, bt, sacc[mj], 0, 0, 0);
        }
      }
      float mx = -1e30f;
#pragma unroll
      for (int mj = 0; mj < 4; ++mj)
#pragma unroll
        for (int r = 0; r < 4; ++r) {
          int j = mj * 16 + lg * 4 + r;
          if (j < 49) mx = fmaxf(mx, sacc[mj][r]);
        }
      mx = fmaxf(mx, __shfl_xor(mx, 16));
      mx = fmaxf(mx, __shfl_xor(mx, 32));
      float p[4][4];
      float sum = 0.f;
#pragma unroll
      for (int mj = 0; mj < 4; ++mj)
#pragma unroll
        for (int r = 0; r < 4; ++r) {
          int j = mj * 16 + lg * 4 + r;
          float e = (j < 49) ? __expf((sacc[mj][r] - mx) * scale) : 0.f;
          p[mj][r] = e;
          sum += e;
        }
      sum += __shfl_xor(sum, 16);
      sum += __shfl_xor(sum, 32);
      float inv = 1.f / sum;
#pragma unroll
      for (int mj = 0; mj < 4; ++mj) {
        bf16x4 pk = { (bf16_t)(p[mj][0] * inv), (bf16_t)(p[mj][1] * inv),
                      (bf16_t)(p[mj][2] * inv), (bf16_t)(p[mj][3] * inv) };
        psave[mj] = pk;
      }
    }
    __syncthreads();   // (3) T reads drained; VOt may overwrite T region
    // ---- Phase VO: VO[c][s] = sum_cin X[s,cin] U[c,cin] (+bu), write VOt.
    // Split per (c-tile, s-half): vacc 8 regs live.
    {
      const bf16_t* U_w = wts + U_OFF_ELEMS;
      const float* bu_h = bu + h * CH;
#pragma unroll
      for (int mi = 0; mi < 3; ++mi) {
        int c = (wm + mi) * 16 + l15;
        float bb = bu_h[c];
#pragma unroll
        for (int sh = 0; sh < 2; ++sh) {
          f32x4 vacc[2] = {};
#pragma unroll
          for (int ks = 0; ks < 6; ++ks) {
            bf16x8 bfu = *(const bf16x8*)&U_w[((((h * 12 + wm + mi) * 6 + ks) << 6) + lane) * 8];
#pragma unroll
            for (int m2 = 0; m2 < 2; ++m2) {
              bf16x8 af = *(const bf16x8*)&Xl[((sh * 2 + m2) * 16 + l15) * XLD + ks * 32 + lg * 8];
              vacc[m2] = __builtin_amdgcn_mfma_f32_16x16x32_bf16(af, bfu, vacc[m2], 0, 0, 0);
            }
          }
#pragma unroll
          for (int m2 = 0; m2 < 2; ++m2) {
            int s0 = (sh * 2 + m2) * 16 + lg * 4;
            bf16x4 pk = { (bf16_t)(vacc[m2][0] + bb), (bf16_t)(vacc[m2][1] + bb),
                          (bf16_t)(vacc[m2][2] + bb), (bf16_t)(vacc[m2][3] + bb) };
            *(bf16x4*)&VOtl[c * ULD + s0] = pk;
          }
        }
      }
    }
    __syncthreads();   // (4) VOt ready
    // ---- Phase Y: yacc[c, t=own i-tile] += sum_s VOt[c,s] P[t,s].
    // B-frag = psave concat (permuted k-slots s = ms*16+lg*4+e);
    // A-frag = VOt read with the SAME permutation (two b64 at ms*16+lg*4).
    {
      bf16x8 bq8[2];
      bq8[0] = __builtin_shufflevector(psave[0], psave[1], 0, 1, 2, 3, 4, 5, 6, 7);
      bq8[1] = __builtin_shufflevector(psave[2], psave[3], 0, 1, 2, 3, 4, 5, 6, 7);
#pragma unroll
      for (int mc = 0; mc < 12; ++mc) {
#pragma unroll
        for (int kp = 0; kp < 2; ++kp) {
          const bf16_t* vr = &VOtl[(mc * 16 + l15) * ULD + kp * 32 + lg * 4];
          bf16x4 a0 = *(const bf16x4*)vr;
          bf16x4 a1 = *(const bf16x4*)(vr + 16);
          bf16x8 av = __builtin_shufflevector(a0, a1, 0, 1, 2, 3, 4, 5, 6, 7);
          yacc[mc] = __builtin_amdgcn_mfma_f32_16x16x32_bf16(av, bq8[kp], yacc[mc], 0, 0, 0);
        }
      }
    }
  }

  // ---- epilogue: +bo, plain-reshape merge + roll(+3,+3), packed f32x4 stores
  {
    int t = wave * 16 + l15;
    if (t < 49) {
      int pos = rem * 49 + t;
      int hp = pos / 112, wp = pos % 112;
      hp += SHIFT; if (hp >= HW) hp -= HW;
      wp += SHIFT; if (wp >= HW) wp -= HW;
      float* op = out + (((b * HW + hp) * HW) + wp) * CH;
#pragma unroll
      for (int mc = 0; mc < 12; ++mc) {
        int c0 = mc * 16 + lg * 4;
        f32x4 v = yacc[mc];
        v[0] += bo[c0]; v[1] += bo[c0 + 1]; v[2] += bo[c0 + 2]; v[3] += bo[c0 + 3];
        *(f32x4*)&op[c0] = v;
      }
    }
  }
}

extern "C" void kernel_launch(void* const* d_in, const int* in_sizes, int n_in,
                              void* d_out, int out_size, void* d_ws, size_t ws_size,
                              hipStream_t stream) {
  const float* x  = (const float*)d_in[0];
  const float* Wq = (const float*)d_in[1];
  const float* bq = (const float*)d_in[2];
  const float* Wk = (const float*)d_in[3];
  const float* Wv = (const float*)d_in[5];
  const float* bv = (const float*)d_in[6];
  const float* Wo = (const float*)d_in[7];
  const float* bo = (const float*)d_in[8];
  float* out = (float*)d_out;
  bf16_t* wts = (bf16_t*)d_ws;                        // Gt | U, swizzled
  float*  bu  = (float*)((char*)d_ws + BU_OFF_BYTES);
  float*  w1  = (float*)((char*)d_ws + W1_OFF_BYTES);

  prep_gt<<<NH * CH, CH, 0, stream>>>(Wq, Wk, wts);
  prep_u<<<NH * CH, CH, 0, stream>>>(Wv, Wo, wts + U_OFF_ELEMS);
  prep_bu<<<NH, CH, 0, stream>>>(bv, Wo, bu);
  prep_w1<<<NH, CH, 0, stream>>>(Wk, bq, w1);

  (void)hipFuncSetAttribute((const void*)swin_fused,
                            hipFuncAttributeMaxDynamicSharedMemorySize, LDS_BYTES);
  swin_fused<<<dim3(4096), dim3(256), LDS_BYTES, stream>>>(x, bo, wts, bu, w1, out);
}